// Round 12
// baseline (4309.198 us; speedup 1.0000x reference)
//
#include <hip/hip_runtime.h>
#include <hip/hip_fp16.h>
#include <cstdint>

#define EPSQ 1e-6f
#define E_LAM 1e-4f

#define B_ 256
#define S_ 512
#define F_ 16
#define C1_ 64
#define C2_ 128
#define C3_ 256
#define HID_ 128

typedef _Float16 f16x8 __attribute__((ext_vector_type(8)));
typedef _Float16 f16x4 __attribute__((ext_vector_type(4)));
typedef float f32x4 __attribute__((ext_vector_type(4)));

__device__ __forceinline__ float sigm(float x){
  return __builtin_amdgcn_rcpf(1.0f + __builtin_amdgcn_exp2f(-1.44269504f*x));
}
__device__ __forceinline__ float tanhft(float x){
  float e = __builtin_amdgcn_exp2f(-2.88539008f*x);
  return (1.0f - e) * __builtin_amdgcn_rcpf(1.0f + e);
}

// opaque-ify a 16B vector value so the compiler cannot rematerialize/sink its load
#define PINV(x) asm volatile("" : "+v"(reinterpret_cast<f32x4&>(x)))

// ---------------- init min/max slots ----------------
__global__ void k_init(unsigned int* mm){
  int t = threadIdx.x;
  if (t < 4) mm[t] = (t & 1) ? 0u : 0x7f800000u;
}

// ---------------- queue layer phase 1 ----------------
__global__ __launch_bounds__(256) void k_queue1(
    const float* __restrict__ x, const float* __restrict__ ksp, const float* __restrict__ kap,
    float* __restrict__ Wq, float* __restrict__ Lq, unsigned int* __restrict__ mm){
  int i = blockIdx.x * 256 + threadIdx.x;
  float ks = ksp[0], ka = kap[0];
  float dist = x[(size_t)i*F_ + 13];
  float air  = x[(size_t)i*F_ + 11];
  float ES  = ks*dist + EPSQ;
  float lam = ka/(air + EPSQ);
  float rho = fminf(lam*ES, 0.99f);
  float wq  = rho/(1.0f - rho + EPSQ)*ES;
  float lq  = lam*wq;
  Wq[i] = wq; Lq[i] = lq;
  float wmin=wq, wmax=wq, lmin=lq, lmax=lq;
  for (int o=32;o;o>>=1){
    wmin = fminf(wmin, __shfl_xor(wmin,o));
    wmax = fmaxf(wmax, __shfl_xor(wmax,o));
    lmin = fminf(lmin, __shfl_xor(lmin,o));
    lmax = fmaxf(lmax, __shfl_xor(lmax,o));
  }
  if ((threadIdx.x & 63) == 0){
    atomicMin(mm+0, __float_as_uint(wmin));
    atomicMax(mm+1, __float_as_uint(wmax));
    atomicMin(mm+2, __float_as_uint(lmin));
    atomicMax(mm+3, __float_as_uint(lmax));
  }
}

// ---------------- queue layer phase 2 ----------------
__global__ __launch_bounds__(256) void k_queue2(
    float* __restrict__ Wq, float* __restrict__ Lq, const unsigned int* __restrict__ mm,
    float* __restrict__ dbar, float* __restrict__ lbar){
  int b = blockIdx.x, t = threadIdx.x;
  float minW = __uint_as_float(mm[0]), maxW = __uint_as_float(mm[1]);
  float minL = __uint_as_float(mm[2]), maxL = __uint_as_float(mm[3]);
  float dW = maxW - minW + EPSQ;
  float dL = maxL - minL + EPSQ;
  float sw = 0.f, sl = 0.f;
  for (int s=t; s<S_; s+=256){
    size_t idx = (size_t)b*S_ + s;
    float wn = (Wq[idx]-minW)/dW;
    float ln = (Lq[idx]-minL)/dL;
    Wq[idx]=wn; Lq[idx]=ln;
    sw += wn; sl += ln;
  }
  for (int o=32;o;o>>=1){ sw += __shfl_xor(sw,o); sl += __shfl_xor(sl,o); }
  __shared__ float rs[4], rl[4];
  int w = t>>6;
  if ((t&63)==0){ rs[w]=sw; rl[w]=sl; }
  __syncthreads();
  if (t==0){
    dbar[b] = (rs[0]+rs[1]+rs[2]+rs[3]) * (1.0f/S_);
    lbar[b] = (rl[0]+rl[1]+rl[2]+rl[3]) * (1.0f/S_);
  }
}

// ---------------- conv weight repack: w[co][ci][k] -> wr[ci][k][co] ----------------
__global__ void k_repack_conv(const float* __restrict__ w, float* __restrict__ wr, int CIN, int COUT){
  int idx = blockIdx.x*256 + threadIdx.x;
  int N = CIN*COUT*3;
  if (idx >= N) return;
  int co = idx % COUT;
  int r  = idx / COUT;
  int k  = r % 3;
  int ci = r / 3;
  wr[idx] = w[((size_t)co*CIN + ci)*3 + k];
}

// ---------------- conv3 weight repack into MFMA B-fragments (f16) ----------------
__global__ void k_repack_w3f(const float* __restrict__ w3, __half* __restrict__ W3f){
  int idx = blockIdx.x*256 + threadIdx.x;    // 256co * 384K = 98304
  if (idx >= 98304) return;
  int f = idx & 7, l = (idx>>3) & 63, t = idx >> 9;
  int kb = t % 12, nt = t / 12;
  int co = nt*16 + (l&15);
  int K  = kb*32 + ((l>>4)<<3) + f;
  int kidx = K >> 7, ci = K & 127;
  W3f[idx] = __float2half(w3[((size_t)co*C2_ + ci)*3 + kidx]);
}

// ---------------- LSTM weight repack into MFMA A-fragments (f16) ----------------
__global__ void k_repack_frags(
    const float* __restrict__ mod_w, const float* __restrict__ w_ih, const float* __restrict__ w_hh,
    const float* __restrict__ b_ih, const float* __restrict__ b_hh, const float* __restrict__ mod_b,
    __half* __restrict__ WIHf, __half* __restrict__ WHHf, __half* __restrict__ MWf,
    float* __restrict__ BG){
  int idx = blockIdx.x*256 + threadIdx.x;
  const int NIH = 32*8*512;
  const int NHH = 32*4*512;
  const int NMW = 16*5*512;
  if (idx < NIH){
    int f = idx & 7, l = (idx>>3)&63; int t = idx>>9; int kk = t & 7; int nt = t>>3;
    int row = nt*16 + (l&15), k = kk*32 + ((l>>4)<<3) + f;
    WIHf[idx] = __float2half(w_ih[(size_t)row*256 + k]);
  } else if (idx < NIH+NHH){
    int j = idx - NIH;
    int f = j&7, l = (j>>3)&63; int t = j>>9; int kk = t&3; int nt = t>>2;
    int row = nt*16 + (l&15), k = kk*32 + ((l>>4)<<3) + f;
    WHHf[j] = __float2half(w_hh[(size_t)row*128 + k]);
  } else if (idx < NIH+NHH+NMW){
    int j = idx - NIH - NHH;
    int f = j&7, l = (j>>3)&63; int t = j>>9; int kk = t%5; int nt = t/5;
    int row = nt*16 + (l&15), k = kk*32 + ((l>>4)<<3) + f;
    float v = (k < 130) ? mod_w[(size_t)row*130 + k] : ((k == 130) ? mod_b[row] : 0.0f);
    MWf[j] = __float2half(v);
  } else if (idx < NIH+NHH+NMW+512){
    int k = idx - NIH-NHH-NMW;
    BG[k] = b_ih[k] + b_hh[k];
  }
}

// ---------------- conv1 (small K): original structure ----------------
template<int CIN, int COUT, int TOUT>
__global__ __launch_bounds__(256) void k_conv(
    const float* __restrict__ in, const float* __restrict__ wr,
    const float* __restrict__ bias, float* __restrict__ out){
  constexpr int SG    = 256/COUT;
  constexpr int STILE = SG*8;
  constexpr int RS    = STILE+4;
  __shared__ __align__(16) float lds[CIN*RS];
  int b = blockIdx.y;
  int s_base = blockIdx.x * STILE;
  int tid = threadIdx.x;
  for (int idx=tid; idx<CIN*(STILE+2); idx+=256){
    int ci = idx & (F_-1);
    int sp = idx >> 4;
    int sg = s_base - 1 + sp;
    float v = (sg>=0 && sg<S_) ? in[((size_t)b*S_+sg)*F_ + ci] : 0.0f;
    lds[ci*RS+sp] = v;
  }
  __syncthreads();
  int co = tid % COUT;
  int sg = tid / COUT;
  int s0 = sg*8;
  float acc[8] = {0,0,0,0,0,0,0,0};
  for (int ci=0; ci<CIN; ci++){
    const float* w = &wr[(ci*3)*COUT + co];
    float w0=w[0], w1=w[COUT], w2=w[2*COUT];
    const float* r = &lds[ci*RS + s0];
    float4 va = *(const float4*)(r);
    float4 vb = *(const float4*)(r+4);
    float2 vc = *(const float2*)(r+8);
    float v[10] = {va.x,va.y,va.z,va.w, vb.x,vb.y,vb.z,vb.w, vc.x,vc.y};
    #pragma unroll
    for (int ss=0; ss<8; ss++) acc[ss] += w0*v[ss] + w1*v[ss+1] + w2*v[ss+2];
  }
  float bb = bias[co];
  float* o = &out[((size_t)b*COUT+co)*S_ + s_base + s0];
  float4 o0 = make_float4(fmaxf(acc[0]+bb,0.f), fmaxf(acc[1]+bb,0.f), fmaxf(acc[2]+bb,0.f), fmaxf(acc[3]+bb,0.f));
  float4 o1 = make_float4(fmaxf(acc[4]+bb,0.f), fmaxf(acc[5]+bb,0.f), fmaxf(acc[6]+bb,0.f), fmaxf(acc[7]+bb,0.f));
  *(float4*)(o)   = o0;
  *(float4*)(o+4) = o1;
}

// ---------------- conv2: register-tiled GEMM-style f32 conv (r7 form) ----------------
template<int CIN, int COUT, int TOUT>
__global__ __launch_bounds__(256) void k_cgemm(
    const float* __restrict__ in, const float* __restrict__ wr,
    const float* __restrict__ bias, const float* __restrict__ gate,
    float* __restrict__ out){
  constexpr int TS   = 64;
  constexpr int RS   = 72;
  constexpr int SPT  = COUT/32;
  constexpr int NCG  = COUT/8;
  constexpr int KC   = (CIN == 64) ? 8 : 4;
  constexpr int WROW = NCG*10;
  __shared__ __align__(16) float sIn[CIN*RS];
  __shared__ __align__(16) float sW[3*KC*WROW];
  int b = blockIdx.y;
  int s_base = blockIdx.x * TS;
  int tid = threadIdx.x;
  for (int idx = tid; idx < CIN*(TS+2); idx += 256){
    int ci = idx / (TS+2), sp = idx % (TS+2);
    int sg = s_base - 1 + sp;
    float v = (sg>=0 && sg<S_) ? in[((size_t)b*CIN+ci)*S_ + sg] : 0.0f;
    sIn[ci*RS + sp] = v * gate[b*CIN + ci];
  }
  int cg = tid % NCG, sg2 = tid / NCG;
  int co0 = cg*8, s0 = sg2*SPT;
  float2 acc[8][SPT/2] = {};
  for (int ci0 = 0; ci0 < CIN; ci0 += KC){
    __syncthreads();
    for (int e = tid; e < 3*KC*COUT; e += 256){
      int krow = e / COUT, co = e % COUT;
      sW[krow*WROW + (co>>3)*10 + (co&7)] = wr[(size_t)3*ci0*COUT + e];
    }
    __syncthreads();
    #pragma unroll
    for (int cii = 0; cii < KC; cii++){
      const float* rp = &sIn[(ci0+cii)*RS + s0];
      float win[SPT+4];
      #pragma unroll
      for (int j = 0; j < (SPT+4)/4; j++)
        *(float4*)&win[4*j] = *(const float4*)(rp + 4*j);
      #pragma unroll
      for (int kidx = 0; kidx < 3; kidx++){
        const float* wrow = &sW[(cii*3 + kidx)*WROW + cg*10];
        float ws[8];
        *(float2*)&ws[0] = *(const float2*)(wrow);
        *(float2*)&ws[2] = *(const float2*)(wrow+2);
        *(float2*)&ws[4] = *(const float2*)(wrow+4);
        *(float2*)&ws[6] = *(const float2*)(wrow+6);
        #pragma unroll
        for (int i = 0; i < 8; i++){
          #pragma unroll
          for (int j = 0; j < SPT/2; j++){
            acc[i][j].x += ws[i]*win[2*j+kidx];
            acc[i][j].y += ws[i]*win[2*j+1+kidx];
          }
        }
      }
    }
  }
  float bs[8];
  *(float4*)&bs[0] = *(const float4*)(bias+co0);
  *(float4*)&bs[4] = *(const float4*)(bias+co0+4);
  #pragma unroll
  for (int i=0;i<8;i++){
    float v[SPT];
    #pragma unroll
    for (int j=0;j<SPT;j++){
      float a = (j&1) ? acc[i][j>>1].y : acc[i][j>>1].x;
      v[j] = fmaxf(a + bs[i], 0.0f);
    }
    float* op = &out[((size_t)b*COUT+co0+i)*S_ + s_base+s0];
    #pragma unroll
    for (int j4=0;j4<SPT;j4+=4) *(float4*)(op+j4) = *(float4*)&v[j4];
  }
}

// ---------------- conv3 via MFMA (r11 form) ----------------
__global__ __launch_bounds__(256) void k_cmfma3(
    const float* __restrict__ z2, const __half* __restrict__ W3f,
    const float* __restrict__ bias, const float* __restrict__ gate,
    float* __restrict__ out){
  __shared__ __align__(16) _Float16 zT[66*128];
  int b = blockIdx.y;
  int s_base = blockIdx.x * 64;
  int tid = threadIdx.x;
  const int lane = tid & 63, w = tid >> 6;
  for (int idx = tid; idx < 128*66; idx += 256){
    int ci = idx / 66, j = idx % 66;
    int sg = s_base + j - 1;
    float v = (sg >= 0 && sg < S_) ? z2[((size_t)b*C2_ + ci)*S_ + sg] * gate[b*C2_ + ci] : 0.0f;
    *(_Float16*)((char*)zT + ((j*256 + ci*2) ^ ((j&7)<<4))) = (_Float16)v;
  }
  __syncthreads();
  f32x4 acc[4][4];
  float bv[4];
  #pragma unroll
  for (int i=0;i<4;i++) bv[i] = bias[(w*4+i)*16 + (lane&15)];
  #pragma unroll
  for (int ts=0;ts<4;ts++)
    #pragma unroll
    for (int i=0;i<4;i++) acc[ts][i] = (f32x4){bv[i],bv[i],bv[i],bv[i]};

  const f16x8* Bf = (const f16x8*)W3f;
  for (int kb=0; kb<12; kb++){
    f16x8 bfr[4];
    #pragma unroll
    for (int i=0;i<4;i++)
      bfr[i] = Bf[(((w*4+i)*12 + kb)<<6) + lane];
    int colb = ((kb&3)*32 + ((lane>>4)<<3))*2;
    f16x8 afr[4];
    #pragma unroll
    for (int ts=0;ts<4;ts++){
      int row = ts*16 + (lane&15) + (kb>>2);
      afr[ts] = *(const f16x8*)((const char*)zT + ((row*256 + colb) ^ ((row&7)<<4)));
    }
    #pragma unroll
    for (int ts=0;ts<4;ts++)
      #pragma unroll
      for (int i=0;i<4;i++)
        acc[ts][i] = __builtin_amdgcn_mfma_f32_16x16x32_f16(afr[ts], bfr[i], acc[ts][i], 0,0,0);
  }
  #pragma unroll
  for (int ts=0; ts<4; ts++){
    #pragma unroll
    for (int i=0; i<4; i++){
      int co = (w*4+i)*16 + (lane&15);
      #pragma unroll
      for (int r=0;r<4;r++){
        int srow = s_base + ts*16 + ((lane>>4)<<2) + r;
        out[((size_t)b*S_ + srow)*C3_ + co] = fmaxf(acc[ts][i][r], 0.0f);
      }
    }
  }
}

// ---------------- SimAM gate (stats only) for (B,C,S) f32 ----------------
template<int C>
__global__ __launch_bounds__(256) void k_gate(
    const float* __restrict__ z, const float* __restrict__ dbar,
    const float* __restrict__ lbar, float* __restrict__ gate){
  int bid = blockIdx.x;
  int b = bid / C, c = bid % C;
  const float* row = z + ((size_t)b*C + c)*S_;
  int t = threadIdx.x;
  float v0 = row[t], v1 = row[t+256];
  float s = v0+v1, q = v0*v0 + v1*v1;
  for (int o=32;o;o>>=1){ s += __shfl_xor(s,o); q += __shfl_xor(q,o); }
  __shared__ float rs[4], rq[4];
  int w = t>>6;
  if ((t&63)==0){ rs[w]=s; rq[w]=q; }
  __syncthreads();
  if (t==0){
    float st = rs[0]+rs[1]+rs[2]+rs[3];
    float qt = rq[0]+rq[1]+rq[2]+rq[3];
    float mu  = st*(1.0f/S_);
    float var = qt*(1.0f/S_) - mu*mu;
    float e = var + dbar[b] + 0.5f*lbar[b] + E_LAM;
    gate[b*C + c] = 1.0f/(1.0f + expf(-e));
  }
}

// ---------------- SimAM for (B,S,C3): stats + in-place multiply ----------------
__global__ __launch_bounds__(1024) void k_simam2(
    float* __restrict__ zt, const float* __restrict__ dbar, const float* __restrict__ lbar){
  int b = blockIdx.x;
  int tid = threadIdx.x;
  int c = tid & 255, part = tid >> 8;
  float* base = zt + ((size_t)b*S_ + part*128)*C3_ + c;
  float s=0.f, q=0.f;
  #pragma unroll 4
  for (int i=0;i<128;i++){ float v = base[(size_t)i*C3_]; s+=v; q+=v*v; }
  __shared__ float S4[4][256], Q4[4][256], gate[256];
  S4[part][c]=s; Q4[part][c]=q;
  __syncthreads();
  if (part==0){
    float st = S4[0][c]+S4[1][c]+S4[2][c]+S4[3][c];
    float qt = Q4[0][c]+Q4[1][c]+Q4[2][c]+Q4[3][c];
    float mu  = st*(1.0f/S_);
    float var = qt*(1.0f/S_) - mu*mu;
    float e = var + dbar[b] + 0.5f*lbar[b] + E_LAM;
    gate[c] = 1.0f/(1.0f+expf(-e));
  }
  __syncthreads();
  float g = gate[c];
  #pragma unroll 4
  for (int i=0;i<128;i++) base[(size_t)i*C3_] *= g;
}

// ---------------- Mogrifier-LSTM via MFMA, 16-wave variant ----------------
// 16 blocks x 1024 threads (16 waves, 4/SIMD). Wave w owns N-tiles {w, w+16}:
// waves 0-7 hold (i,g), waves 8-15 hold (f,o) for the same c-range 16w..16w+15.
// Wih(16)+Whh(8)+mog(5) frags ALL register-pinned (29 frags = 116 regs/wave).
// LDS only MS + H(dbuf) + sigm(f)/sigm(o) exchange = ~34 KB. 3 barriers/step.
// Numerics identical to r8 (sigm f/o pass through f32 LDS exactly).
#define L2_MS_STRIDE 528
#define L2_H_OFF     (16*L2_MS_STRIDE)          // 8448
#define L2_H_STRIDE  272
#define L2_H_BUF     (16*L2_H_STRIDE)           // 4352
#define L2_SF_OFF    (L2_H_OFF + 2*L2_H_BUF)    // 17152
#define L2_SB_STRIDE 528
#define L2_SO_OFF    (L2_SF_OFF + 16*L2_SB_STRIDE)  // 25600
#define L2_SMEM      (L2_SO_OFF + 16*L2_SB_STRIDE)  // 34048

__global__ __launch_bounds__(1024) __attribute__((amdgpu_waves_per_eu(4, 4)))
void k_lstm_mfma2(
    const float* __restrict__ zt, const float* __restrict__ Wn, const float* __restrict__ Ln,
    const __half* __restrict__ WIHf, const __half* __restrict__ WHHf, const __half* __restrict__ MWf,
    const float* __restrict__ BG, const float* __restrict__ cls_w, const float* __restrict__ cls_b,
    float* __restrict__ out){
  __shared__ __align__(16) char smem[L2_SMEM];
  const int tid = threadIdx.x;
  const int lane = tid & 63, w = tid >> 6;        // w in [0,16)
  const int batch = lane & 15, kq = lane >> 4;
  const int b0 = blockIdx.x * 16;
  const bool lowg = (w < 8);

  // ---- register-pinned frags: Wih 2x8, Whh 2x4, mog 5 ----
  const f16x8* WIHv = (const f16x8*)WIHf;
  const f16x8* WHHv = (const f16x8*)WHHf;
  const f16x8* MWv  = (const f16x8*)MWf;
  f16x8 wihr[2][8];
  #pragma unroll
  for (int t2=0; t2<2; t2++)
    #pragma unroll
    for (int kk=0; kk<8; kk++)
      wihr[t2][kk] = WIHv[((((w + t2*16)*8) + kk)<<6) + lane];
  f16x8 whr[2][4];
  #pragma unroll
  for (int t2=0; t2<2; t2++)
    #pragma unroll
    for (int kk=0; kk<4; kk++)
      whr[t2][kk] = WHHv[((((w + t2*16)*4) + kk)<<6) + lane];
  f16x8 mgr[5];
  #pragma unroll
  for (int kk=0; kk<5; kk++)
    mgr[kk] = MWv[(((w*5) + kk)<<6) + lane];
  #pragma unroll
  for (int t2=0; t2<2; t2++){
    #pragma unroll
    for (int kk=0; kk<8; kk++) PINV(wihr[t2][kk]);
    #pragma unroll
    for (int kk=0; kk<4; kk++) PINV(whr[t2][kk]);
  }
  #pragma unroll
  for (int kk=0; kk<5; kk++) PINV(mgr[kk]);

  f32x4 bgv[2];
  bgv[0] = *(const f32x4*)(BG + w*16 + kq*4);
  bgv[1] = *(const f32x4*)(BG + (w+16)*16 + kq*4);

  for (int i=tid; i<2*L2_H_BUF/4; i+=1024)
    ((unsigned int*)(smem + L2_H_OFF))[i] = 0u;

  const float* zb  = zt + (size_t)(b0 + batch)*S_*C3_;
  const float* wnp = Wn + (size_t)(b0 + batch)*S_;
  const float* lnp = Ln + (size_t)(b0 + batch)*S_;
  const int c0 = w*16 + kq*4;

  char*       ms_w  = smem + batch*L2_MS_STRIDE + w*32 + kq*8;
  const char* ms_rd = smem + batch*L2_MS_STRIDE + kq*16;
  char*       h_wr  = smem + L2_H_OFF + batch*L2_H_STRIDE + w*32 + kq*8;   // waves 0-7
  const char* h_rd  = smem + L2_H_OFF + batch*L2_H_STRIDE + kq*16;
  char*       sf_wr = smem + L2_SF_OFF + batch*L2_SB_STRIDE + ((w-8)*16 + kq*4)*4;
  char*       so_wr = smem + L2_SO_OFF + batch*L2_SB_STRIDE + ((w-8)*16 + kq*4)*4;
  const char* sf_rd = smem + L2_SF_OFF + batch*L2_SB_STRIDE + (w*16 + kq*4)*4;
  const char* so_rd = smem + L2_SO_OFF + batch*L2_SB_STRIDE + (w*16 + kq*4)*4;

  f32x4 cst = {0.f,0.f,0.f,0.f};
  f32x4 hv  = {0.f,0.f,0.f,0.f};

  f32x4 zvc = *(const f32x4*)(zb + c0);
  float dvc = wnp[0], lvc = lnp[0];
  __syncthreads();

  for (int t=0; t<S_; t++){
    const int p = t & 1;
    const char* hrd = h_rd + p*L2_H_BUF;
    f16x8 hb0[4];
    #pragma unroll
    for (int kk=0; kk<4; kk++)
      hb0[kk] = *(const f16x8*)(hrd + kk*64);
    f16x8 dlb = {0,0,0,0,0,0,0,0};
    if (kq == 0){ dlb[0] = (_Float16)dvc; dlb[1] = (_Float16)lvc; dlb[2] = (_Float16)1.0f; }
    // ---- mogrifier GEMM (1 tile, 5 pinned frags) ----
    f32x4 am = {0,0,0,0};
    #pragma unroll
    for (int kk=0; kk<4; kk++)
      am = __builtin_amdgcn_mfma_f32_16x16x32_f16(mgr[kk], hb0[kk], am, 0,0,0);
    am = __builtin_amdgcn_mfma_f32_16x16x32_f16(mgr[4], dlb, am, 0,0,0);
    f16x4 msv;
    #pragma unroll
    for (int r=0;r<4;r++) msv[r] = (_Float16)(sigm(am[r]) * zvc[r]);
    *(f16x4*)ms_w = msv;
    // ---- acc init + Whh while waves converge ----
    f32x4 acc[2];
    acc[0] = bgv[0]; acc[1] = bgv[1];
    #pragma unroll
    for (int kk=0; kk<4; kk++){
      acc[0] = __builtin_amdgcn_mfma_f32_16x16x32_f16(whr[0][kk], hb0[kk], acc[0], 0,0,0);
      acc[1] = __builtin_amdgcn_mfma_f32_16x16x32_f16(whr[1][kk], hb0[kk], acc[1], 0,0,0);
    }
    __syncthreads();   // barrier1: MS visible
    int tn = (t+1 < S_) ? t+1 : t;
    zvc = *(const f32x4*)(zb + (size_t)tn*C3_ + c0);
    dvc = wnp[tn]; lvc = lnp[tn];
    // ---- Wih on MS ----
    f16x8 mscur = *(const f16x8*)(ms_rd);
    #pragma unroll
    for (int kk=0; kk<8; kk++){
      f16x8 msn;
      if (kk < 7) msn = *(const f16x8*)(ms_rd + (kk+1)*64);
      acc[0] = __builtin_amdgcn_mfma_f32_16x16x32_f16(wihr[0][kk], mscur, acc[0], 0,0,0);
      acc[1] = __builtin_amdgcn_mfma_f32_16x16x32_f16(wihr[1][kk], mscur, acc[1], 0,0,0);
      if (kk < 7) mscur = msn;
    }
    // ---- gate exchange + cell update ----
    if (!lowg){
      f32x4 sf, so;
      #pragma unroll
      for (int r=0;r<4;r++){ sf[r] = sigm(acc[0][r]); so[r] = sigm(acc[1][r]); }
      *(f32x4*)sf_wr = sf;
      *(f32x4*)so_wr = so;
    }
    __syncthreads();   // barrier2: sf/so visible
    if (lowg){
      f32x4 sf = *(const f32x4*)sf_rd;
      f32x4 so = *(const f32x4*)so_rd;
      f16x4 hp;
      #pragma unroll
      for (int r=0; r<4; r++){
        float si = sigm(acc[0][r]);
        float tg = tanhft(acc[1][r]);
        float cc = sf[r]*cst[r] + si*tg;
        cst[r] = cc;
        float hh = so[r]*tanhft(cc);
        hv[r] = hh;
        hp[r] = (_Float16)hh;
      }
      *(f16x4*)(h_wr + (p^1)*L2_H_BUF) = hp;
    }
    __syncthreads();   // barrier3: H ready
  }
  // classifier: h lives in waves 0-7
  if (lowg) *(f32x4*)(smem + batch*512 + w*64 + kq*16) = hv;
  __syncthreads();
  if (tid < 128){
    int bb = tid >> 3, oo = tid & 7;
    const float* hf = (const float*)smem + bb*128;
    float a = cls_b[oo];
    #pragma unroll 16
    for (int k2=0; k2<HID_; k2++) a += hf[k2]*cls_w[oo*HID_+k2];
    out[(b0+bb)*8 + oo] = a;
  }
}

extern "C" void kernel_launch(void* const* d_in, const int* in_sizes, int n_in,
                              void* d_out, int out_size, void* d_ws, size_t ws_size,
                              hipStream_t stream){
  const float* x     = (const float*)d_in[0];
  const float* k_s   = (const float*)d_in[1];
  const float* k_a   = (const float*)d_in[2];
  const float* w1    = (const float*)d_in[3];
  const float* b1    = (const float*)d_in[4];
  const float* w2    = (const float*)d_in[5];
  const float* b2    = (const float*)d_in[6];
  const float* w3    = (const float*)d_in[7];
  const float* b3    = (const float*)d_in[8];
  const float* mod_w = (const float*)d_in[9];
  const float* mod_b = (const float*)d_in[10];
  const float* w_ih  = (const float*)d_in[11];
  const float* w_hh  = (const float*)d_in[12];
  const float* b_ih  = (const float*)d_in[13];
  const float* b_hh  = (const float*)d_in[14];
  const float* cls_w = (const float*)d_in[15];
  const float* cls_b = (const float*)d_in[16];
  float* outp = (float*)d_out;

  char* ws = (char*)d_ws;
  size_t o = 0;
  auto alloc = [&](size_t bytes){ size_t r = o; o = (o + bytes + 255) & ~(size_t)255; return r; };
  float*        Wq   = (float*)(ws + alloc((size_t)B_*S_*4));
  float*        Lq   = (float*)(ws + alloc((size_t)B_*S_*4));
  unsigned int* MM   = (unsigned int*)(ws + alloc(16));
  float*        DB   = (float*)(ws + alloc(B_*4));
  float*        LB   = (float*)(ws + alloc(B_*4));
  float*        WR1  = (float*)(ws + alloc((size_t)F_*3*C1_*4));
  float*        WR2  = (float*)(ws + alloc((size_t)C1_*3*C2_*4));
  __half*       W3f  = (__half*)(ws + alloc((size_t)98304*2));
  __half*       WIHf = (__half*)(ws + alloc((size_t)32*8*512*2));
  __half*       WHHf = (__half*)(ws + alloc((size_t)32*4*512*2));
  __half*       MWf  = (__half*)(ws + alloc((size_t)16*5*512*2));
  float*        BG   = (float*)(ws + alloc(512*4));
  float*        G1   = (float*)(ws + alloc((size_t)B_*C1_*4));
  float*        G2   = (float*)(ws + alloc((size_t)B_*C2_*4));
  float*        Z1   = (float*)(ws + alloc((size_t)B_*C1_*S_*4));
  float*        Z2   = (float*)(ws + alloc((size_t)B_*C2_*S_*4));
  float*        ZT3  = (float*)(ws + alloc((size_t)B_*S_*C3_*4));
  (void)ws_size; (void)in_sizes; (void)n_in; (void)out_size;

  hipLaunchKernelGGL(k_init, dim3(1), dim3(64), 0, stream, MM);
  hipLaunchKernelGGL(k_queue1, dim3((B_*S_)/256), dim3(256), 0, stream, x, k_s, k_a, Wq, Lq, MM);
  hipLaunchKernelGGL(k_queue2, dim3(B_), dim3(256), 0, stream, Wq, Lq, MM, DB, LB);

  hipLaunchKernelGGL(k_repack_conv, dim3((F_*3*C1_+255)/256), dim3(256), 0, stream, w1, WR1, F_, C1_);
  hipLaunchKernelGGL(k_repack_conv, dim3((C1_*3*C2_+255)/256), dim3(256), 0, stream, w2, WR2, C1_, C2_);
  hipLaunchKernelGGL(k_repack_w3f, dim3((98304+255)/256), dim3(256), 0, stream, w3, W3f);
  {
    int N = 32*8*512 + 32*4*512 + 16*5*512 + 512;
    hipLaunchKernelGGL(k_repack_frags, dim3((N+255)/256), dim3(256), 0, stream,
                       mod_w, w_ih, w_hh, b_ih, b_hh, mod_b, WIHf, WHHf, MWf, BG);
  }

  hipLaunchKernelGGL((k_conv<F_, C1_, 0>), dim3(S_/32, B_), dim3(256), 0, stream, x,  WR1, b1, Z1);
  hipLaunchKernelGGL((k_gate<C1_>), dim3(B_*C1_), dim3(256), 0, stream, Z1, DB, LB, G1);
  hipLaunchKernelGGL((k_cgemm<C1_, C2_, 0>), dim3(S_/64, B_), dim3(256), 0, stream, Z1, WR2, b2, G1, Z2);
  hipLaunchKernelGGL((k_gate<C2_>), dim3(B_*C2_), dim3(256), 0, stream, Z2, DB, LB, G2);
  hipLaunchKernelGGL(k_cmfma3, dim3(S_/64, B_), dim3(256), 0, stream, Z2, W3f, b3, G2, ZT3);
  hipLaunchKernelGGL(k_simam2, dim3(B_), dim3(1024), 0, stream, ZT3, DB, LB);

  hipLaunchKernelGGL(k_lstm_mfma2, dim3(B_/16), dim3(1024), 0, stream,
                     ZT3, Wq, Lq, WIHf, WHHf, MWf, BG, cls_w, cls_b, outp);
}

// Round 13
// 1390.718 us; speedup vs baseline: 3.0985x; 3.0985x over previous
//
#include <hip/hip_runtime.h>
#include <hip/hip_fp16.h>
#include <cstdint>

#define EPSQ 1e-6f
#define E_LAM 1e-4f

#define B_ 256
#define S_ 512
#define F_ 16
#define C1_ 64
#define C2_ 128
#define C3_ 256
#define HID_ 128

typedef _Float16 f16x8 __attribute__((ext_vector_type(8)));
typedef _Float16 f16x4 __attribute__((ext_vector_type(4)));
typedef float f32x4 __attribute__((ext_vector_type(4)));

__device__ __forceinline__ float sigm(float x){
  return __builtin_amdgcn_rcpf(1.0f + __builtin_amdgcn_exp2f(-1.44269504f*x));
}
__device__ __forceinline__ float tanhft(float x){
  float e = __builtin_amdgcn_exp2f(-2.88539008f*x);
  return (1.0f - e) * __builtin_amdgcn_rcpf(1.0f + e);
}

// opaque-ify a 16B vector value so the compiler cannot rematerialize/sink its load
#define PINV(x) asm volatile("" : "+v"(reinterpret_cast<f32x4&>(x)))

// ---------------- init min/max slots ----------------
__global__ void k_init(unsigned int* mm){
  int t = threadIdx.x;
  if (t < 4) mm[t] = (t & 1) ? 0u : 0x7f800000u;
}

// ---------------- queue layer phase 1 ----------------
__global__ __launch_bounds__(256) void k_queue1(
    const float* __restrict__ x, const float* __restrict__ ksp, const float* __restrict__ kap,
    float* __restrict__ Wq, float* __restrict__ Lq, unsigned int* __restrict__ mm){
  int i = blockIdx.x * 256 + threadIdx.x;
  float ks = ksp[0], ka = kap[0];
  float dist = x[(size_t)i*F_ + 13];
  float air  = x[(size_t)i*F_ + 11];
  float ES  = ks*dist + EPSQ;
  float lam = ka/(air + EPSQ);
  float rho = fminf(lam*ES, 0.99f);
  float wq  = rho/(1.0f - rho + EPSQ)*ES;
  float lq  = lam*wq;
  Wq[i] = wq; Lq[i] = lq;
  float wmin=wq, wmax=wq, lmin=lq, lmax=lq;
  for (int o=32;o;o>>=1){
    wmin = fminf(wmin, __shfl_xor(wmin,o));
    wmax = fmaxf(wmax, __shfl_xor(wmax,o));
    lmin = fminf(lmin, __shfl_xor(lmin,o));
    lmax = fmaxf(lmax, __shfl_xor(lmax,o));
  }
  if ((threadIdx.x & 63) == 0){
    atomicMin(mm+0, __float_as_uint(wmin));
    atomicMax(mm+1, __float_as_uint(wmax));
    atomicMin(mm+2, __float_as_uint(lmin));
    atomicMax(mm+3, __float_as_uint(lmax));
  }
}

// ---------------- queue layer phase 2 ----------------
__global__ __launch_bounds__(256) void k_queue2(
    float* __restrict__ Wq, float* __restrict__ Lq, const unsigned int* __restrict__ mm,
    float* __restrict__ dbar, float* __restrict__ lbar){
  int b = blockIdx.x, t = threadIdx.x;
  float minW = __uint_as_float(mm[0]), maxW = __uint_as_float(mm[1]);
  float minL = __uint_as_float(mm[2]), maxL = __uint_as_float(mm[3]);
  float dW = maxW - minW + EPSQ;
  float dL = maxL - minL + EPSQ;
  float sw = 0.f, sl = 0.f;
  for (int s=t; s<S_; s+=256){
    size_t idx = (size_t)b*S_ + s;
    float wn = (Wq[idx]-minW)/dW;
    float ln = (Lq[idx]-minL)/dL;
    Wq[idx]=wn; Lq[idx]=ln;
    sw += wn; sl += ln;
  }
  for (int o=32;o;o>>=1){ sw += __shfl_xor(sw,o); sl += __shfl_xor(sl,o); }
  __shared__ float rs[4], rl[4];
  int w = t>>6;
  if ((t&63)==0){ rs[w]=sw; rl[w]=sl; }
  __syncthreads();
  if (t==0){
    dbar[b] = (rs[0]+rs[1]+rs[2]+rs[3]) * (1.0f/S_);
    lbar[b] = (rl[0]+rl[1]+rl[2]+rl[3]) * (1.0f/S_);
  }
}

// ---------------- conv1 weight repack: w[co][ci][k] -> wr[ci][k][co] ----------------
__global__ void k_repack_conv(const float* __restrict__ w, float* __restrict__ wr, int CIN, int COUT){
  int idx = blockIdx.x*256 + threadIdx.x;
  int N = CIN*COUT*3;
  if (idx >= N) return;
  int co = idx % COUT;
  int r  = idx / COUT;
  int k  = r % 3;
  int ci = r / 3;
  wr[idx] = w[((size_t)co*CIN + ci)*3 + k];
}

// ---------------- conv2 weight repack into MFMA B-fragments (f16) ----------------
// B-frag (16x16x32): lane l holds B[K = kb*32 + (l>>4)*8 + f][col = l&15].
// K in [0,192): kidx = K/64, ci = K%64. flat idx ((nt*6+kb)*64 + l)*8 + f.
__global__ void k_repack_w2f(const float* __restrict__ w2, __half* __restrict__ W2f){
  int idx = blockIdx.x*256 + threadIdx.x;    // 128co * 192K = 24576
  if (idx >= 24576) return;
  int f = idx & 7, l = (idx>>3) & 63, t = idx >> 9;
  int kb = t % 6, nt = t / 6;
  int co = nt*16 + (l&15);
  int K  = kb*32 + ((l>>4)<<3) + f;
  int kidx = K >> 6, ci = K & 63;
  W2f[idx] = __float2half(w2[((size_t)co*C1_ + ci)*3 + kidx]);
}

// ---------------- conv3 weight repack into MFMA B-fragments (f16) ----------------
__global__ void k_repack_w3f(const float* __restrict__ w3, __half* __restrict__ W3f){
  int idx = blockIdx.x*256 + threadIdx.x;    // 256co * 384K = 98304
  if (idx >= 98304) return;
  int f = idx & 7, l = (idx>>3) & 63, t = idx >> 9;
  int kb = t % 12, nt = t / 12;
  int co = nt*16 + (l&15);
  int K  = kb*32 + ((l>>4)<<3) + f;
  int kidx = K >> 7, ci = K & 127;
  W3f[idx] = __float2half(w3[((size_t)co*C2_ + ci)*3 + kidx]);
}

// ---------------- LSTM weight repack into MFMA A-fragments (f16) ----------------
__global__ void k_repack_frags(
    const float* __restrict__ mod_w, const float* __restrict__ w_ih, const float* __restrict__ w_hh,
    const float* __restrict__ b_ih, const float* __restrict__ b_hh, const float* __restrict__ mod_b,
    __half* __restrict__ WIHf, __half* __restrict__ WHHf, __half* __restrict__ MWf,
    float* __restrict__ BG){
  int idx = blockIdx.x*256 + threadIdx.x;
  const int NIH = 32*8*512;
  const int NHH = 32*4*512;
  const int NMW = 16*5*512;
  if (idx < NIH){
    int f = idx & 7, l = (idx>>3)&63; int t = idx>>9; int kk = t & 7; int nt = t>>3;
    int row = nt*16 + (l&15), k = kk*32 + ((l>>4)<<3) + f;
    WIHf[idx] = __float2half(w_ih[(size_t)row*256 + k]);
  } else if (idx < NIH+NHH){
    int j = idx - NIH;
    int f = j&7, l = (j>>3)&63; int t = j>>9; int kk = t&3; int nt = t>>2;
    int row = nt*16 + (l&15), k = kk*32 + ((l>>4)<<3) + f;
    WHHf[j] = __float2half(w_hh[(size_t)row*128 + k]);
  } else if (idx < NIH+NHH+NMW){
    int j = idx - NIH - NHH;
    int f = j&7, l = (j>>3)&63; int t = j>>9; int kk = t%5; int nt = t/5;
    int row = nt*16 + (l&15), k = kk*32 + ((l>>4)<<3) + f;
    float v = (k < 130) ? mod_w[(size_t)row*130 + k] : ((k == 130) ? mod_b[row] : 0.0f);
    MWf[j] = __float2half(v);
  } else if (idx < NIH+NHH+NMW+512){
    int k = idx - NIH-NHH-NMW;
    BG[k] = b_ih[k] + b_hh[k];
  }
}

// ---------------- conv1 (small K): original structure ----------------
template<int CIN, int COUT, int TOUT>
__global__ __launch_bounds__(256) void k_conv(
    const float* __restrict__ in, const float* __restrict__ wr,
    const float* __restrict__ bias, float* __restrict__ out){
  constexpr int SG    = 256/COUT;
  constexpr int STILE = SG*8;
  constexpr int RS    = STILE+4;
  __shared__ __align__(16) float lds[CIN*RS];
  int b = blockIdx.y;
  int s_base = blockIdx.x * STILE;
  int tid = threadIdx.x;
  for (int idx=tid; idx<CIN*(STILE+2); idx+=256){
    int ci = idx & (F_-1);
    int sp = idx >> 4;
    int sg = s_base - 1 + sp;
    float v = (sg>=0 && sg<S_) ? in[((size_t)b*S_+sg)*F_ + ci] : 0.0f;
    lds[ci*RS+sp] = v;
  }
  __syncthreads();
  int co = tid % COUT;
  int sg = tid / COUT;
  int s0 = sg*8;
  float acc[8] = {0,0,0,0,0,0,0,0};
  for (int ci=0; ci<CIN; ci++){
    const float* w = &wr[(ci*3)*COUT + co];
    float w0=w[0], w1=w[COUT], w2=w[2*COUT];
    const float* r = &lds[ci*RS + s0];
    float4 va = *(const float4*)(r);
    float4 vb = *(const float4*)(r+4);
    float2 vc = *(const float2*)(r+8);
    float v[10] = {va.x,va.y,va.z,va.w, vb.x,vb.y,vb.z,vb.w, vc.x,vc.y};
    #pragma unroll
    for (int ss=0; ss<8; ss++) acc[ss] += w0*v[ss] + w1*v[ss+1] + w2*v[ss+2];
  }
  float bb = bias[co];
  float* o = &out[((size_t)b*COUT+co)*S_ + s_base + s0];
  float4 o0 = make_float4(fmaxf(acc[0]+bb,0.f), fmaxf(acc[1]+bb,0.f), fmaxf(acc[2]+bb,0.f), fmaxf(acc[3]+bb,0.f));
  float4 o1 = make_float4(fmaxf(acc[4]+bb,0.f), fmaxf(acc[5]+bb,0.f), fmaxf(acc[6]+bb,0.f), fmaxf(acc[7]+bb,0.f));
  *(float4*)(o)   = o0;
  *(float4*)(o+4) = o1;
}

// ---------------- conv2 via MFMA ----------------
// Block = (batch, 64-s tile), 256 thr (4 waves). D[64s x 128co] = A_im2col[64x192] @ W2[192x64->128].
// A: LDS zT1[66][64] f16 (gate1 folded, XOR-swizzled). B: W2f frag-linear (48KB, L2-hot).
// f32 accum, bias+relu, float4 stores to (B,C2,S) (quarter-wave covers full cachelines).
__global__ __launch_bounds__(256) void k_cmfma2(
    const float* __restrict__ z1, const __half* __restrict__ W2f,
    const float* __restrict__ bias, const float* __restrict__ gate,
    float* __restrict__ out){
  __shared__ __align__(16) _Float16 zT1[66*64];
  int b = blockIdx.y;
  int s_base = blockIdx.x * 64;
  int tid = threadIdx.x;
  const int lane = tid & 63, w = tid >> 6;
  for (int idx = tid; idx < 64*66; idx += 256){
    int ci = idx / 66, j = idx % 66;
    int sg = s_base + j - 1;
    float v = (sg >= 0 && sg < S_) ? z1[((size_t)b*C1_ + ci)*S_ + sg] * gate[b*C1_ + ci] : 0.0f;
    *(_Float16*)((char*)zT1 + ((j*128 + ci*2) ^ ((j&7)<<4))) = (_Float16)v;
  }
  __syncthreads();
  // wave w owns co-tiles {2w, 2w+1}; 4 s-tiles
  f32x4 acc[4][2];
  float bv[2];
  #pragma unroll
  for (int i=0;i<2;i++) bv[i] = bias[(w*2+i)*16 + (lane&15)];
  #pragma unroll
  for (int ts=0;ts<4;ts++)
    #pragma unroll
    for (int i=0;i<2;i++) acc[ts][i] = (f32x4){bv[i],bv[i],bv[i],bv[i]};

  const f16x8* Bf = (const f16x8*)W2f;
  for (int kb=0; kb<6; kb++){
    f16x8 bfr[2];
    #pragma unroll
    for (int i=0;i<2;i++)
      bfr[i] = Bf[(((w*2+i)*6 + kb)<<6) + lane];
    int colb = ((kb&1)*32 + ((lane>>4)<<3))*2;
    f16x8 afr[4];
    #pragma unroll
    for (int ts=0;ts<4;ts++){
      int row = ts*16 + (lane&15) + (kb>>1);
      afr[ts] = *(const f16x8*)((const char*)zT1 + ((row*128 + colb) ^ ((row&7)<<4)));
    }
    #pragma unroll
    for (int ts=0;ts<4;ts++)
      #pragma unroll
      for (int i=0;i<2;i++)
        acc[ts][i] = __builtin_amdgcn_mfma_f32_16x16x32_f16(afr[ts], bfr[i], acc[ts][i], 0,0,0);
  }
  // D[row=(l>>4)*4+r][col=l&15]; relu + float4 store along s to (B,C2,S)
  #pragma unroll
  for (int ts=0; ts<4; ts++){
    #pragma unroll
    for (int i=0; i<2; i++){
      int co = (w*2+i)*16 + (lane&15);
      int srow = s_base + ts*16 + ((lane>>4)<<2);
      float4 v4 = make_float4(fmaxf(acc[ts][i][0],0.f), fmaxf(acc[ts][i][1],0.f),
                              fmaxf(acc[ts][i][2],0.f), fmaxf(acc[ts][i][3],0.f));
      *(float4*)&out[((size_t)b*C2_ + co)*S_ + srow] = v4;
    }
  }
}

// ---------------- conv3 via MFMA (r11 form) ----------------
__global__ __launch_bounds__(256) void k_cmfma3(
    const float* __restrict__ z2, const __half* __restrict__ W3f,
    const float* __restrict__ bias, const float* __restrict__ gate,
    float* __restrict__ out){
  __shared__ __align__(16) _Float16 zT[66*128];
  int b = blockIdx.y;
  int s_base = blockIdx.x * 64;
  int tid = threadIdx.x;
  const int lane = tid & 63, w = tid >> 6;
  for (int idx = tid; idx < 128*66; idx += 256){
    int ci = idx / 66, j = idx % 66;
    int sg = s_base + j - 1;
    float v = (sg >= 0 && sg < S_) ? z2[((size_t)b*C2_ + ci)*S_ + sg] * gate[b*C2_ + ci] : 0.0f;
    *(_Float16*)((char*)zT + ((j*256 + ci*2) ^ ((j&7)<<4))) = (_Float16)v;
  }
  __syncthreads();
  f32x4 acc[4][4];
  float bv[4];
  #pragma unroll
  for (int i=0;i<4;i++) bv[i] = bias[(w*4+i)*16 + (lane&15)];
  #pragma unroll
  for (int ts=0;ts<4;ts++)
    #pragma unroll
    for (int i=0;i<4;i++) acc[ts][i] = (f32x4){bv[i],bv[i],bv[i],bv[i]};

  const f16x8* Bf = (const f16x8*)W3f;
  for (int kb=0; kb<12; kb++){
    f16x8 bfr[4];
    #pragma unroll
    for (int i=0;i<4;i++)
      bfr[i] = Bf[(((w*4+i)*12 + kb)<<6) + lane];
    int colb = ((kb&3)*32 + ((lane>>4)<<3))*2;
    f16x8 afr[4];
    #pragma unroll
    for (int ts=0;ts<4;ts++){
      int row = ts*16 + (lane&15) + (kb>>2);
      afr[ts] = *(const f16x8*)((const char*)zT + ((row*256 + colb) ^ ((row&7)<<4)));
    }
    #pragma unroll
    for (int ts=0;ts<4;ts++)
      #pragma unroll
      for (int i=0;i<4;i++)
        acc[ts][i] = __builtin_amdgcn_mfma_f32_16x16x32_f16(afr[ts], bfr[i], acc[ts][i], 0,0,0);
  }
  #pragma unroll
  for (int ts=0; ts<4; ts++){
    #pragma unroll
    for (int i=0; i<4; i++){
      int co = (w*4+i)*16 + (lane&15);
      #pragma unroll
      for (int r=0;r<4;r++){
        int srow = s_base + ts*16 + ((lane>>4)<<2) + r;
        out[((size_t)b*S_ + srow)*C3_ + co] = fmaxf(acc[ts][i][r], 0.0f);
      }
    }
  }
}

// ---------------- SimAM gate (stats only) for (B,C,S) f32 ----------------
template<int C>
__global__ __launch_bounds__(256) void k_gate(
    const float* __restrict__ z, const float* __restrict__ dbar,
    const float* __restrict__ lbar, float* __restrict__ gate){
  int bid = blockIdx.x;
  int b = bid / C, c = bid % C;
  const float* row = z + ((size_t)b*C + c)*S_;
  int t = threadIdx.x;
  float v0 = row[t], v1 = row[t+256];
  float s = v0+v1, q = v0*v0 + v1*v1;
  for (int o=32;o;o>>=1){ s += __shfl_xor(s,o); q += __shfl_xor(q,o); }
  __shared__ float rs[4], rq[4];
  int w = t>>6;
  if ((t&63)==0){ rs[w]=s; rq[w]=q; }
  __syncthreads();
  if (t==0){
    float st = rs[0]+rs[1]+rs[2]+rs[3];
    float qt = rq[0]+rq[1]+rq[2]+rq[3];
    float mu  = st*(1.0f/S_);
    float var = qt*(1.0f/S_) - mu*mu;
    float e = var + dbar[b] + 0.5f*lbar[b] + E_LAM;
    gate[b*C + c] = 1.0f/(1.0f + expf(-e));
  }
}

// ---------------- SimAM for (B,S,C3): stats + in-place multiply ----------------
__global__ __launch_bounds__(1024) void k_simam2(
    float* __restrict__ zt, const float* __restrict__ dbar, const float* __restrict__ lbar){
  int b = blockIdx.x;
  int tid = threadIdx.x;
  int c = tid & 255, part = tid >> 8;
  float* base = zt + ((size_t)b*S_ + part*128)*C3_ + c;
  float s=0.f, q=0.f;
  #pragma unroll 4
  for (int i=0;i<128;i++){ float v = base[(size_t)i*C3_]; s+=v; q+=v*v; }
  __shared__ float S4[4][256], Q4[4][256], gate[256];
  S4[part][c]=s; Q4[part][c]=q;
  __syncthreads();
  if (part==0){
    float st = S4[0][c]+S4[1][c]+S4[2][c]+S4[3][c];
    float qt = Q4[0][c]+Q4[1][c]+Q4[2][c]+Q4[3][c];
    float mu  = st*(1.0f/S_);
    float var = qt*(1.0f/S_) - mu*mu;
    float e = var + dbar[b] + 0.5f*lbar[b] + E_LAM;
    gate[c] = 1.0f/(1.0f+expf(-e));
  }
  __syncthreads();
  float g = gate[c];
  #pragma unroll 4
  for (int i=0;i<128;i++) base[(size_t)i*C3_] *= g;
}

// ---------------- Mogrifier-LSTM via MFMA (r8 form — FROZEN) ----------------
// Failed variants: setprio (r5, +230us+pathology), gate-fold (r6, +230us),
// f16 z-path (r9, +260us), 16-wave/4-per-SIMD (r12, +2760us, regalloc broke
// frag pinning at 128-reg budget). 2-wave/SIMD latency-critical: do not touch.
#define MOG_OFF   0
#define MS_OFF    81920
#define MS_STRIDE 528
#define H_OFF     (MS_OFF + 16*MS_STRIDE)
#define H_STRIDE  272
#define H_BUF     (16*H_STRIDE)
#define BG_OFF    (H_OFF + 2*H_BUF)
#define SMEM_SZ   (BG_OFF + 2048)

__global__ __launch_bounds__(512) __attribute__((amdgpu_waves_per_eu(2, 2)))
void k_lstm_mfma(
    const float* __restrict__ zt, const float* __restrict__ Wn, const float* __restrict__ Ln,
    const __half* __restrict__ WIHf, const __half* __restrict__ WHHf, const __half* __restrict__ MWf,
    const float* __restrict__ BG, const float* __restrict__ cls_w, const float* __restrict__ cls_b,
    float* __restrict__ out){
  __shared__ __align__(16) char smem[SMEM_SZ];
  const int tid = threadIdx.x;
  const int lane = tid & 63, w = tid >> 6;
  const int batch = lane & 15, kq = lane >> 4;
  const int b0 = blockIdx.x * 16;

  {
    const f32x4* src = (const f32x4*)MWf;
    for (int i = tid; i < 5120; i += 512)
      *(f32x4*)(smem + MOG_OFF + (size_t)i*16) = src[i];
    int wq = tid >> 6, rem = tid & 63, kq2 = rem >> 4, j = rem & 15, g = j >> 2, r = j & 3;
    ((float*)(smem + BG_OFF))[tid] = BG[g*128 + wq*16 + kq2*4 + r];
    for (int i = tid; i < 2*H_BUF/4; i += 512)
      ((unsigned int*)(smem + H_OFF))[i] = 0u;
  }

  const f16x8* WIHv = (const f16x8*)WIHf;
  const f16x8* WHHv = (const f16x8*)WHHf;
  f16x8 wihr[8][4];
  #pragma unroll
  for (int kk=0; kk<8; kk++)
    #pragma unroll
    for (int g=0; g<4; g++)
      wihr[kk][g] = WIHv[(((w + g*8)*8 + kk)<<6) + lane];
  f16x8 whr[4][4];
  #pragma unroll
  for (int g=0; g<4; g++)
    #pragma unroll
    for (int kk=0; kk<4; kk++)
      whr[g][kk] = WHHv[(((w + g*8)*4 + kk)<<6) + lane];
  #pragma unroll
  for (int kk=0; kk<8; kk++)
    #pragma unroll
    for (int g=0; g<4; g++) PINV(wihr[kk][g]);
  #pragma unroll
  for (int g=0; g<4; g++)
    #pragma unroll
    for (int kk=0; kk<4; kk++) PINV(whr[g][kk]);

  const float* zb  = zt + (size_t)(b0 + batch)*S_*C3_;
  const float* wnp = Wn + (size_t)(b0 + batch)*S_;
  const float* lnp = Ln + (size_t)(b0 + batch)*S_;

  char*       ms_w0 = smem + MS_OFF + batch*MS_STRIDE + (2*w+0)*32 + kq*8;
  char*       ms_w1 = smem + MS_OFF + batch*MS_STRIDE + (2*w+1)*32 + kq*8;
  const char* ms_rd = smem + MS_OFF + batch*MS_STRIDE + kq*16;
  char*       h_wr  = smem + H_OFF + batch*H_STRIDE + w*32 + kq*8;
  const char* h_rd  = smem + H_OFF + batch*H_STRIDE + kq*16;
  const float* bgp  = (const float*)(smem + BG_OFF) + (w*4 + kq)*16;
  const char* mogp  = smem + MOG_OFF + lane*16;

  f32x4 cst = {0.f,0.f,0.f,0.f};
  f32x4 hv  = {0.f,0.f,0.f,0.f};

  f32x4 zv0c = *(const f32x4*)(zb + (2*w+0)*16 + kq*4);
  f32x4 zv1c = *(const f32x4*)(zb + (2*w+1)*16 + kq*4);
  float dvc = wnp[0], lvc = lnp[0];
  __syncthreads();

  for (int t=0; t<S_; t++){
    const int p = t & 1;
    const char* hrd = h_rd + p*H_BUF;
    f16x8 hb0[4];
    #pragma unroll
    for (int kk=0; kk<4; kk++)
      hb0[kk] = *(const f16x8*)(hrd + kk*64);
    f16x8 dlb = {0,0,0,0,0,0,0,0};
    if (kq == 0){ dlb[0] = (_Float16)dvc; dlb[1] = (_Float16)lvc; dlb[2] = (_Float16)1.0f; }
    // ---- mogrifier GEMM ----
    f32x4 am0 = {0,0,0,0}, am1 = {0,0,0,0};
    f16x8 mg0 = *(const f16x8*)(mogp + (((2*w+0)*5 + 0)<<10));
    f16x8 mg1 = *(const f16x8*)(mogp + (((2*w+1)*5 + 0)<<10));
    #pragma unroll
    for (int kk=0; kk<5; kk++){
      f16x8 n0, n1;
      if (kk < 4){
        n0 = *(const f16x8*)(mogp + (((2*w+0)*5 + kk+1)<<10));
        n1 = *(const f16x8*)(mogp + (((2*w+1)*5 + kk+1)<<10));
      }
      f16x8 bfr = (kk < 4) ? hb0[kk] : dlb;
      am0 = __builtin_amdgcn_mfma_f32_16x16x32_f16(mg0, bfr, am0, 0,0,0);
      am1 = __builtin_amdgcn_mfma_f32_16x16x32_f16(mg1, bfr, am1, 0,0,0);
      if (kk < 4){ mg0 = n0; mg1 = n1; }
    }
    f16x4 msv;
    #pragma unroll
    for (int r=0;r<4;r++) msv[r] = (_Float16)(sigm(am0[r]) * zv0c[r]);
    *(f16x4*)ms_w0 = msv;
    #pragma unroll
    for (int r=0;r<4;r++) msv[r] = (_Float16)(sigm(am1[r]) * zv1c[r]);
    *(f16x4*)ms_w1 = msv;
    // ---- acc init + Whh while waves converge on barrier ----
    f32x4 acc[4];
    #pragma unroll
    for (int g=0; g<4; g++) acc[g] = *(const f32x4*)(bgp + g*4);
    #pragma unroll
    for (int kk=0; kk<4; kk++){
      #pragma unroll
      for (int g=0; g<4; g++)
        acc[g] = __builtin_amdgcn_mfma_f32_16x16x32_f16(whr[g][kk], hb0[kk], acc[g], 0,0,0);
    }
    __syncthreads();   // MS visible
    int tn = (t+1 < S_) ? t+1 : t;
    zv0c = *(const f32x4*)(zb + (size_t)tn*C3_ + (2*w+0)*16 + kq*4);
    zv1c = *(const f32x4*)(zb + (size_t)tn*C3_ + (2*w+1)*16 + kq*4);
    dvc = wnp[tn]; lvc = lnp[tn];
    // ---- Wih on MS ----
    f16x8 mscur = *(const f16x8*)(ms_rd);
    #pragma unroll
    for (int kk=0; kk<8; kk++){
      f16x8 msn;
      if (kk < 7) msn = *(const f16x8*)(ms_rd + (kk+1)*64);
      #pragma unroll
      for (int g=0; g<4; g++)
        acc[g] = __builtin_amdgcn_mfma_f32_16x16x32_f16(wihr[kk][g], mscur, acc[g], 0,0,0);
      if (kk < 7) mscur = msn;
    }
    // ---- cell update ----
    #pragma unroll
    for (int r=0; r<4; r++){
      float cc = sigm(acc[1][r]) * cst[r] + sigm(acc[0][r]) * tanhft(acc[2][r]);
      cst[r] = cc;
      hv[r] = sigm(acc[3][r]) * tanhft(cc);
    }
    f16x4 hp;
    #pragma unroll
    for (int r=0;r<4;r++) hp[r] = (_Float16)hv[r];
    *(f16x4*)(h_wr + (p^1)*H_BUF) = hp;
    __syncthreads();   // H ready for next step
  }
  *(f32x4*)(smem + MS_OFF + batch*512 + w*64 + kq*16) = hv;
  __syncthreads();
  if (tid < 128){
    int bb = tid >> 3, oo = tid & 7;
    const float* hf = (const float*)(smem + MS_OFF) + bb*128;
    float a = cls_b[oo];
    #pragma unroll 16
    for (int k2=0; k2<HID_; k2++) a += hf[k2]*cls_w[oo*HID_+k2];
    out[(b0+bb)*8 + oo] = a;
  }
}

extern "C" void kernel_launch(void* const* d_in, const int* in_sizes, int n_in,
                              void* d_out, int out_size, void* d_ws, size_t ws_size,
                              hipStream_t stream){
  const float* x     = (const float*)d_in[0];
  const float* k_s   = (const float*)d_in[1];
  const float* k_a   = (const float*)d_in[2];
  const float* w1    = (const float*)d_in[3];
  const float* b1    = (const float*)d_in[4];
  const float* w2    = (const float*)d_in[5];
  const float* b2    = (const float*)d_in[6];
  const float* w3    = (const float*)d_in[7];
  const float* b3    = (const float*)d_in[8];
  const float* mod_w = (const float*)d_in[9];
  const float* mod_b = (const float*)d_in[10];
  const float* w_ih  = (const float*)d_in[11];
  const float* w_hh  = (const float*)d_in[12];
  const float* b_ih  = (const float*)d_in[13];
  const float* b_hh  = (const float*)d_in[14];
  const float* cls_w = (const float*)d_in[15];
  const float* cls_b = (const float*)d_in[16];
  float* outp = (float*)d_out;

  char* ws = (char*)d_ws;
  size_t o = 0;
  auto alloc = [&](size_t bytes){ size_t r = o; o = (o + bytes + 255) & ~(size_t)255; return r; };
  float*        Wq   = (float*)(ws + alloc((size_t)B_*S_*4));
  float*        Lq   = (float*)(ws + alloc((size_t)B_*S_*4));
  unsigned int* MM   = (unsigned int*)(ws + alloc(16));
  float*        DB   = (float*)(ws + alloc(B_*4));
  float*        LB   = (float*)(ws + alloc(B_*4));
  float*        WR1  = (float*)(ws + alloc((size_t)F_*3*C1_*4));
  __half*       W2f  = (__half*)(ws + alloc((size_t)24576*2));
  __half*       W3f  = (__half*)(ws + alloc((size_t)98304*2));
  __half*       WIHf = (__half*)(ws + alloc((size_t)32*8*512*2));
  __half*       WHHf = (__half*)(ws + alloc((size_t)32*4*512*2));
  __half*       MWf  = (__half*)(ws + alloc((size_t)16*5*512*2));
  float*        BG   = (float*)(ws + alloc(512*4));
  float*        G1   = (float*)(ws + alloc((size_t)B_*C1_*4));
  float*        G2   = (float*)(ws + alloc((size_t)B_*C2_*4));
  float*        Z1   = (float*)(ws + alloc((size_t)B_*C1_*S_*4));
  float*        Z2   = (float*)(ws + alloc((size_t)B_*C2_*S_*4));
  float*        ZT3  = (float*)(ws + alloc((size_t)B_*S_*C3_*4));
  (void)ws_size; (void)in_sizes; (void)n_in; (void)out_size;

  hipLaunchKernelGGL(k_init, dim3(1), dim3(64), 0, stream, MM);
  hipLaunchKernelGGL(k_queue1, dim3((B_*S_)/256), dim3(256), 0, stream, x, k_s, k_a, Wq, Lq, MM);
  hipLaunchKernelGGL(k_queue2, dim3(B_), dim3(256), 0, stream, Wq, Lq, MM, DB, LB);

  hipLaunchKernelGGL(k_repack_conv, dim3((F_*3*C1_+255)/256), dim3(256), 0, stream, w1, WR1, F_, C1_);
  hipLaunchKernelGGL(k_repack_w2f, dim3((24576+255)/256), dim3(256), 0, stream, w2, W2f);
  hipLaunchKernelGGL(k_repack_w3f, dim3((98304+255)/256), dim3(256), 0, stream, w3, W3f);
  {
    int N = 32*8*512 + 32*4*512 + 16*5*512 + 512;
    hipLaunchKernelGGL(k_repack_frags, dim3((N+255)/256), dim3(256), 0, stream,
                       mod_w, w_ih, w_hh, b_ih, b_hh, mod_b, WIHf, WHHf, MWf, BG);
  }

  hipLaunchKernelGGL((k_conv<F_, C1_, 0>), dim3(S_/32, B_), dim3(256), 0, stream, x,  WR1, b1, Z1);
  hipLaunchKernelGGL((k_gate<C1_>), dim3(B_*C1_), dim3(256), 0, stream, Z1, DB, LB, G1);
  hipLaunchKernelGGL(k_cmfma2, dim3(S_/64, B_), dim3(256), 0, stream, Z1, W2f, b2, G1, Z2);
  hipLaunchKernelGGL((k_gate<C2_>), dim3(B_*C2_), dim3(256), 0, stream, Z2, DB, LB, G2);
  hipLaunchKernelGGL(k_cmfma3, dim3(S_/64, B_), dim3(256), 0, stream, Z2, W3f, b3, G2, ZT3);
  hipLaunchKernelGGL(k_simam2, dim3(B_), dim3(1024), 0, stream, ZT3, DB, LB);

  hipLaunchKernelGGL(k_lstm_mfma, dim3(B_/16), dim3(512), 0, stream,
                     ZT3, Wq, Lq, WIHf, WHHf, MWf, BG, cls_w, cls_b, outp);
}